// Round 8
// baseline (655.936 us; speedup 1.0000x reference)
//
#include <hip/hip_runtime.h>
#include <cstdint>

typedef unsigned short u16;
typedef __attribute__((ext_vector_type(8))) short short8;   // 8 bf16 (4 VGPRs)
typedef __attribute__((ext_vector_type(4))) float f32x4;

constexpr int kB = 4, kT = 2048, kC = 512, kV = 32000;
constexpr int kBT = kB * kT;                 // 8192
constexpr float kScale = 0.044194173824159216f;  // C^-0.5

__device__ __forceinline__ u16 f2b(float f) {
  union { float f; unsigned u; } v; v.f = f;
  unsigned r = v.u + 0x7fffu + ((v.u >> 16) & 1u);   // RNE
  return (u16)(r >> 16);
}

// async global->LDS, 16B per lane. LDS dest is wave-uniform base + lane*16.
__device__ __forceinline__ void g2lds16(const u16* g, u16* l) {
  __builtin_amdgcn_global_load_lds(
      (const __attribute__((address_space(1))) void*)g,
      (__attribute__((address_space(3))) void*)l, 16, 0, 0);
}

// ---------------- weight transpose + bf16 cast: in f32 [R][Ncol] -> out bf16 [Ncol][R]
__global__ __launch_bounds__(256) void transpose_cast(const float* __restrict__ in,
                                                      u16* __restrict__ out,
                                                      int R, int Ncol) {
  __shared__ u16 tile[32][33];
  int c0 = blockIdx.x * 32, r0 = blockIdx.y * 32;
  int tx = threadIdx.x, ty = threadIdx.y;   // (32,8)
#pragma unroll
  for (int j = 0; j < 32; j += 8)
    tile[ty + j][tx] = f2b(in[(long)(r0 + ty + j) * Ncol + (c0 + tx)]);
  __syncthreads();
#pragma unroll
  for (int j = 0; j < 32; j += 8)
    out[(long)(c0 + ty + j) * R + (r0 + tx)] = tile[tx][ty + j];
}

// ---------------- embedding: x_bf16[b*T+t][c] = token_emb[idx][c] + pos_emb[t][c]
__global__ __launch_bounds__(128) void embed_kernel(const int* __restrict__ idx,
                                                    const float* __restrict__ te,
                                                    const float* __restrict__ pe,
                                                    u16* __restrict__ xb) {
  int row = blockIdx.x;            // b*T + t
  int t = row & (kT - 1);
  int tok = idx[row];
  int c = threadIdx.x * 4;
  float4 a = *(const float4*)(te + (long)tok * kC + c);
  float4 p = *(const float4*)(pe + (long)t * kC + c);
  ushort4 o;
  o.x = f2b(a.x + p.x); o.y = f2b(a.y + p.y);
  o.z = f2b(a.z + p.z); o.w = f2b(a.w + p.w);
  *(ushort4*)(xb + (long)row * kC + c) = o;
}

// ---------------- 128^2-tile bf16 MFMA GEMM (m97 structure) for QKV/S/PV
// OUT_MODE: 0 = f32 out (+bias), 1 = bf16 out, 2 = bf16 out transposed (out[n][m])
// KCAP: causal K-limit — only K-steps with k < m0+128 contribute.
template <int OUT_MODE, bool CAUSAL, bool KCAP>
__global__ __launch_bounds__(256) void gemm_bt(
    const u16* __restrict__ A, const u16* __restrict__ Bt, void* __restrict__ OutP,
    const float* __restrict__ bias,
    int M, int N, int K, int lda, int ldb, int ldo,
    long batchA, long batchB, long batchO, float alpha) {
  int bz = blockIdx.z;
  A += bz * batchA;
  Bt += bz * batchB;
  int m0 = blockIdx.y * 128, n0 = blockIdx.x * 128;
  if (CAUSAL && n0 > m0 + 127) return;   // tile fully above causal diagonal

  __shared__ u16 As[2][128 * 32];
  __shared__ u16 Bs[2][128 * 32];
  int tid = threadIdx.x;
  int lane = tid & 63, w = tid >> 6;
  int wr = w >> 1, wc = w & 1;           // 2x2 wave grid, each wave 64x64 out
  int lm = lane & 15, lk = lane >> 4;

  f32x4 acc[4][4] = {};

  const u16* aptr = A + (long)(m0 + (w << 4) + (lane >> 2)) * lda + ((lane & 3) << 3);
  const u16* bptr = Bt + (long)(n0 + (w << 4) + (lane >> 2)) * ldb + ((lane & 3) << 3);

#define STAGE(buf)                                                   \
  {                                                                  \
    g2lds16(aptr,                  &As[buf][(w << 4) * 32]);         \
    g2lds16(aptr + (long)64 * lda, &As[buf][(64 + (w << 4)) * 32]);  \
    g2lds16(bptr,                  &Bs[buf][(w << 4) * 32]);         \
    g2lds16(bptr + (long)64 * ldb, &Bs[buf][(64 + (w << 4)) * 32]);  \
  }

  int nk = K >> 5;
  if (KCAP) { int cap = (m0 >> 5) + 4; nk = (cap < nk) ? cap : nk; }
  STAGE(0);
  __syncthreads();

  for (int kt = 0; kt < nk; ++kt) {
    int cur = kt & 1;
    aptr += 32; bptr += 32;
    if (kt + 1 < nk) STAGE(cur ^ 1);
    short8 af[4], bf[4];
#pragma unroll
    for (int i = 0; i < 4; ++i) {
      af[i] = *(const short8*)&As[cur][(wr * 64 + i * 16 + lm) * 32 + lk * 8];
      bf[i] = *(const short8*)&Bs[cur][(wc * 64 + i * 16 + lm) * 32 + lk * 8];
    }
#pragma unroll
    for (int mi = 0; mi < 4; ++mi)
#pragma unroll
      for (int ni = 0; ni < 4; ++ni)
        acc[mi][ni] = __builtin_amdgcn_mfma_f32_16x16x32_bf16(af[mi], bf[ni], acc[mi][ni], 0, 0, 0);
    __syncthreads();
  }
#undef STAGE

#pragma unroll
  for (int mi = 0; mi < 4; ++mi) {
#pragma unroll
    for (int ni = 0; ni < 4; ++ni) {
      int row = m0 + wr * 64 + mi * 16 + lk * 4;
      int col = n0 + wc * 64 + ni * 16 + lm;
      if (OUT_MODE == 0) {
        float* Out = (float*)OutP + bz * batchO;
        float bv = bias ? bias[col] : 0.0f;
#pragma unroll
        for (int r = 0; r < 4; ++r)
          Out[(long)(row + r) * ldo + col] = acc[mi][ni][r] * alpha + bv;
      } else if (OUT_MODE == 1) {
        u16* Out = (u16*)OutP + bz * batchO;
#pragma unroll
        for (int r = 0; r < 4; ++r)
          Out[(long)(row + r) * ldo + col] = f2b(acc[mi][ni][r] * alpha);
      } else {
        u16* Out = (u16*)OutP + bz * batchO;
        ushort4 pk;
        pk.x = f2b(acc[mi][ni][0] * alpha);
        pk.y = f2b(acc[mi][ni][1] * alpha);
        pk.z = f2b(acc[mi][ni][2] * alpha);
        pk.w = f2b(acc[mi][ni][3] * alpha);
        *(ushort4*)&Out[(long)col * ldo + row] = pk;
      }
    }
  }
}

// ---------------- 256x128-tile BK=32 logits GEMM + fused CE partials
// logits[8192][32000] = attn[8192][512] @ wot[32000][512]^T + bo
// Geometry: 8 waves (2 wm x 4 wn), per-wave out 128x32, acc = 64 VGPR.
// LDS 48 KB (A: 2buf x 2half x 8KB, B: 2buf x 8KB) -> 2 blocks/CU:
//   epilogue stores of block X overlap K-loop MFMA of co-resident block Y
//   (the round-7 kernel's 128KB LDS forced 1 block/CU -> ~166us of f32
//    stores fully serialized after compute).
// At BK=32 (64B rows) each fragment ds_read covers a contiguous 1024B
// region (16 rows x 64B, distinct 16B/lane) -> conflict-free, NO swizzle;
// staging is linear on both sides (rule #21 trivially satisfied).
// Schedule (2 phases/K-tile, counted vmcnt):
//   pA(t): read A0-3(t),B0-1(t); stage A0,A1(t+1) -> OTHER buffer (dead
//          since end of t-1) ; barrier; lgkmcnt(0); 8 MFMA; barrier.
//   pB(t): read A4-7(t); stage B(t+2) -> cur buffer (B(t) fully read:
//          pA's per-wave lgkmcnt(0) + pA exit barrier); barrier;
//          lgkmcnt(0); 8 MFMA; boundary wait; barrier.
// Boundary invariant: outstanding = {B(t+1), A0(t+1), A1(t+1), B(t+2)};
//   pA(t+1) needs the first three -> vmcnt(1). Prologue: issue
//   {A0(0),A1(0),B(0),B(1)}, vmcnt(1). Tail: t==nk-2 -> vmcnt(0).
__global__ __launch_bounds__(512, 4) void gemm_logits_ce(
    const u16* __restrict__ A, const u16* __restrict__ Bt,
    float* __restrict__ Out, const float* __restrict__ bias,
    float2* __restrict__ cepart) {
  constexpr int lda = kC, ldb = kC, ldo = kV;
  constexpr int nk = kC / 32;          // 16 K-tiles
  constexpr int NBce = kV / 128;       // 250 CE col-blocks

  __shared__ u16 lds[24576];           // bytes: A [buf*16384 + half*8192]; B 32768 + buf*8192

  // XCD-aware L2 blocking: grid 8000 = 8 xcd x (4 by x 250 bx); per-XCD
  // A-set (4 x 256-row panels = 1 MB) stays L2-resident across the bx sweep.
  int wg = blockIdx.x;
  int xcd = wg & 7;
  int i = wg >> 3;                     // 0..999
  int by = xcd * 4 + (i & 3);          // 0..31
  int bx = i >> 2;                     // 0..249
  int m0 = by * 256, n0 = bx * 128;

  int tid = threadIdx.x;
  int lane = tid & 63, w = tid >> 6;
  int wm = w >> 2, wn = w & 3;         // wave: rows wm*128+128, cols wn*32+32
  int lm = lane & 15, lk = lane >> 4;

  // staging map (linear): thread tid -> row tid>>2 (0..127), 16B chunk tid&3
  int srow = tid >> 2;
  int schunk = (tid & 3) * 8;          // u16 offset within 32-wide k-slab
  const u16* Arow = A + (long)(m0 + srow) * lda + schunk;
  const u16* Brow = Bt + (long)(n0 + srow) * ldb + schunk;

  f32x4 acc[8][2] = {};
  short8 aF[4], bF[2];

  auto stageA = [&](int tile, int half) {
    if (tile >= nk) return;
    u16* base = &lds[(tile & 1) * 8192 + half * 4096 + w * 512];
    g2lds16(Arow + (long)half * 128 * lda + tile * 32, base);
  };
  auto stageB = [&](int tile) {
    if (tile >= nk) return;
    u16* base = &lds[16384 + (tile & 1) * 4096 + w * 512];
    g2lds16(Brow + tile * 32, base);
  };

  // prologue: A0(0), A1(0), B(0), B(1); wait all but newest (B(1)).
  stageA(0, 0); stageA(0, 1); stageB(0); stageB(1);
  asm volatile("s_waitcnt vmcnt(1)" ::: "memory");
  __builtin_amdgcn_sched_barrier(0);
  __builtin_amdgcn_s_barrier();

#pragma unroll 2
  for (int t = 0; t < nk; ++t) {
    int cur = t & 1;
    const char* Ab = (const char*)lds + cur * 16384 + wm * 8192;
    const char* Bb = (const char*)lds + 32768 + cur * 8192;

#define RDA(rf) (*(const short8*)(Ab + (((rf)*16 + lm) * 64) + lk * 16))
#define RDB(cf) (*(const short8*)(Bb + ((wn * 32 + (cf)*16 + lm) * 64) + lk * 16))

    { // phase A: rf0-3 x cf0-1 ; stage A(t+1) -> other buffer
#pragma unroll
      for (int rf = 0; rf < 4; ++rf) aF[rf] = RDA(rf);
      bF[0] = RDB(0); bF[1] = RDB(1);
      stageA(t + 1, 0); stageA(t + 1, 1);
      __builtin_amdgcn_s_barrier();
      asm volatile("s_waitcnt lgkmcnt(0)" ::: "memory");
      __builtin_amdgcn_s_setprio(1);
#pragma unroll
      for (int rf = 0; rf < 4; ++rf)
#pragma unroll
        for (int cf = 0; cf < 2; ++cf)
          acc[rf][cf] = __builtin_amdgcn_mfma_f32_16x16x32_bf16(aF[rf], bF[cf], acc[rf][cf], 0, 0, 0);
      __builtin_amdgcn_s_setprio(0);
      __builtin_amdgcn_s_barrier();
    }
    { // phase B: rf4-7 x cf0-1 ; stage B(t+2) -> cur buffer (B(t) dead)
#pragma unroll
      for (int rf = 0; rf < 4; ++rf) aF[rf] = RDA(rf + 4);
      stageB(t + 2);
      __builtin_amdgcn_s_barrier();
      asm volatile("s_waitcnt lgkmcnt(0)" ::: "memory");
      __builtin_amdgcn_s_setprio(1);
#pragma unroll
      for (int rf = 0; rf < 4; ++rf)
#pragma unroll
        for (int cf = 0; cf < 2; ++cf)
          acc[rf + 4][cf] = __builtin_amdgcn_mfma_f32_16x16x32_bf16(aF[rf], bF[cf], acc[rf + 4][cf], 0, 0, 0);
      __builtin_amdgcn_s_setprio(0);
      if (t < nk - 2) {
        asm volatile("s_waitcnt vmcnt(1)" ::: "memory");
        __builtin_amdgcn_sched_barrier(0);
      } else if (t == nk - 2) {
        asm volatile("s_waitcnt vmcnt(0)" ::: "memory");
        __builtin_amdgcn_sched_barrier(0);
      }
      __builtin_amdgcn_s_barrier();
    }
#undef RDA
#undef RDB
  }

  // epilogue: D col=lane&15, row=(lane>>4)*4+reg. Nontemporal f32 stores
  // (streamed 1.05 GB must not evict L2 A/B panels). CE partials per wave
  // -> LDS -> one float2 per (row, 128-col block).
  float2* lds_ce = (float2*)lds;       // [wm*4+wn][128] ; GEMM LDS dead
#pragma unroll
  for (int rf = 0; rf < 8; ++rf) {
    int grow = m0 + wm * 128 + rf * 16 + lk * 4;
    float rm[4], rs[4];
#pragma unroll
    for (int r = 0; r < 4; ++r) { rm[r] = -1e30f; rs[r] = 0.0f; }
#pragma unroll
    for (int cf = 0; cf < 2; ++cf) {
      int col = n0 + wn * 32 + cf * 16 + lm;
      float bv = bias[col];
#pragma unroll
      for (int r = 0; r < 4; ++r) {
        float v = acc[rf][cf][r] + bv;
        __builtin_nontemporal_store(v, &Out[(long)(grow + r) * ldo + col]);
        float M = fmaxf(rm[r], v);
        rs[r] = rs[r] * __expf(rm[r] - M) + __expf(v - M);
        rm[r] = M;
      }
    }
#pragma unroll
    for (int off = 1; off < 16; off <<= 1) {
#pragma unroll
      for (int r = 0; r < 4; ++r) {
        float om = __shfl_xor(rm[r], off, 64);
        float os = __shfl_xor(rs[r], off, 64);
        float M = fmaxf(rm[r], om);
        rs[r] = rs[r] * __expf(rm[r] - M) + os * __expf(om - M);
        rm[r] = M;
      }
    }
    if (lm == 0) {
#pragma unroll
      for (int r = 0; r < 4; ++r)
        lds_ce[(wm * 4 + wn) * 128 + rf * 16 + lk * 4 + r] = make_float2(rm[r], rs[r]);
    }
  }
  __syncthreads();
  // combine the 4 column-waves per row -> one partial per (row, 128-col block)
  if (tid < 256) {
    int wmg = tid >> 7, r128 = tid & 127;
    float m = -1e30f, s = 0.0f;
#pragma unroll
    for (int j = 0; j < 4; ++j) {
      float2 v = lds_ce[(wmg * 4 + j) * 128 + r128];
      float M = fmaxf(m, v.x);
      s = s * __expf(m - M) + v.y * __expf(v.x - M);
      m = M;
    }
    cepart[(long)(m0 + tid) * NBce + bx] = make_float2(m, s);
  }
}

// ---------------- causal row softmax: S f32 (pre-scaled) -> P bf16
// Writes only cols [0, rowtile_end) — PV's causal K-cap never reads beyond.
__global__ __launch_bounds__(256) void softmax_causal(const float* __restrict__ S,
                                                      u16* __restrict__ P) {
  int row = blockIdx.x;               // b*T + t
  int t = row & (kT - 1);
  int lim = ((t >> 7) + 1) << 7;      // row-tile end (multiple of 128)
  const float* srow = S + (long)row * kT;
  u16* prow = P + (long)row * kT;
  __shared__ float buf[kT];
  __shared__ float red[256];
  int tid = threadIdx.x;
  float mx = -1e30f;
  for (int s = tid; s < lim; s += 256) {
    float v = (s <= t) ? srow[s] : -1e30f;
    buf[s] = v;
    mx = fmaxf(mx, v);
  }
  red[tid] = mx; __syncthreads();
  for (int o = 128; o > 0; o >>= 1) {
    if (tid < o) red[tid] = fmaxf(red[tid], red[tid + o]);
    __syncthreads();
  }
  mx = red[0]; __syncthreads();
  float sm = 0.0f;
  for (int s = tid; s < lim; s += 256) {
    float e = (s <= t) ? __expf(buf[s] - mx) : 0.0f;
    buf[s] = e;
    sm += e;
  }
  red[tid] = sm; __syncthreads();
  for (int o = 128; o > 0; o >>= 1) {
    if (tid < o) red[tid] += red[tid + o];
    __syncthreads();
  }
  float inv = 1.0f / red[0];
  for (int s = tid; s < lim; s += 256) prow[s] = f2b(buf[s] * inv);
}

// ---------------- CE reduce: combine per-colblock (max,sumexp) partials, one wave/row
__global__ __launch_bounds__(256) void ce_reduce(const float* __restrict__ logits,
                                                 const float2* __restrict__ part,
                                                 const int* __restrict__ targets,
                                                 float* __restrict__ nll, int P) {
  int row = blockIdx.x * 4 + (threadIdx.x >> 6);
  int lane = threadIdx.x & 63;
  const float2* pr = part + (long)row * P;
  float m = -1e30f, s = 0.0f;
  for (int p = lane; p < P; p += 64) {
    float2 v = pr[p];
    float M = fmaxf(m, v.x);
    s = s * __expf(m - M) + v.y * __expf(v.x - M);
    m = M;
  }
#pragma unroll
  for (int off = 1; off < 64; off <<= 1) {
    float om = __shfl_xor(m, off, 64), os = __shfl_xor(s, off, 64);
    float M = fmaxf(m, om);
    s = s * __expf(m - M) + os * __expf(om - M);
    m = M;
  }
  if (lane == 0) {
    float lse = m + __logf(s);
    nll[row] = lse - logits[(long)row * kV + targets[row]];
  }
}

__global__ __launch_bounds__(256) void loss_reduce(const float* __restrict__ nll,
                                                   float* __restrict__ out) {
  __shared__ float red[256];
  int tid = threadIdx.x;
  float s = 0.0f;
  for (int i = tid; i < kBT; i += 256) s += nll[i];
  red[tid] = s; __syncthreads();
  for (int o = 128; o > 0; o >>= 1) {
    if (tid < o) red[tid] += red[tid + o];
    __syncthreads();
  }
  if (tid == 0) out[0] = red[0] / (float)kBT;
}

extern "C" void kernel_launch(void* const* d_in, const int* in_sizes, int n_in,
                              void* d_out, int out_size, void* d_ws, size_t ws_size,
                              hipStream_t stream) {
  const int* idx       = (const int*)d_in[0];
  const int* targets   = (const int*)d_in[1];
  const float* token_e = (const float*)d_in[2];
  const float* pos_e   = (const float*)d_in[3];
  const float* Wk      = (const float*)d_in[4];   // note: Wk before Wq in dict order
  const float* Wq      = (const float*)d_in[5];
  const float* Wv      = (const float*)d_in[6];
  const float* Wo      = (const float*)d_in[7];
  const float* bo      = (const float*)d_in[8];
  float* out = (float*)d_out;

  // ---- workspace layout (all bf16 except nll)
  char* ws = (char*)d_ws;
  size_t need = 0;
  auto alloc = [&](size_t bytes) { char* p = ws + need; need += (bytes + 255) & ~(size_t)255; return p; };
  u16* xb   = (u16*)alloc((size_t)kBT * kC * 2);
  u16* wqt  = (u16*)alloc((size_t)kC * kC * 2);   // wqt/wkt contiguous (batched q+k GEMM)
  u16* wkt  = (u16*)alloc((size_t)kC * kC * 2);
  u16* wvt  = (u16*)alloc((size_t)kC * kC * 2);
  u16* wot  = (u16*)alloc((size_t)kV * kC * 2);
  u16* qb   = (u16*)alloc((size_t)kBT * kC * 2);  // qb/kb contiguous (batched out + cepart overlay)
  u16* kb   = (u16*)alloc((size_t)kBT * kC * 2);
  u16* vt   = (u16*)alloc((size_t)kC * kBT * 2);  // v transposed: [C][B*T]
  u16* attn = (u16*)alloc((size_t)kBT * kC * 2);
  float* nll = (float*)alloc((size_t)kBT * 4);
  if (ws_size < need) return;

  // CE partials: 8192 rows x 250 colblocks x 8B = 16.38 MB <= qb+kb (16.78 MB, both dead).
  float2* cepart = (float2*)qb;

  // ---- scratch inside d_out (overwritten by logits GEMM later)
  float* Sbuf = out;                                    // 67 MB f32
  u16* Pbuf   = (u16*)((char*)d_out + (100ull << 20));  // 33.5 MB bf16 @ +100MB

  dim3 tb(32, 8);
  transpose_cast<<<dim3(kC / 32, kC / 32), tb, 0, stream>>>(Wq, wqt, kC, kC);
  transpose_cast<<<dim3(kC / 32, kC / 32), tb, 0, stream>>>(Wk, wkt, kC, kC);
  transpose_cast<<<dim3(kC / 32, kC / 32), tb, 0, stream>>>(Wv, wvt, kC, kC);
  transpose_cast<<<dim3(kV / 32, kC / 32), tb, 0, stream>>>(Wo, wot, kC, kV);

  embed_kernel<<<kBT, 128, 0, stream>>>(idx, token_e, pos_e, xb);

  // q and k in one batched launch (z=0 -> wqt/qb, z=1 -> wkt/kb); v transposed out.
  gemm_bt<1, false, false><<<dim3(4, 64, 2), 256, 0, stream>>>(xb, wqt, qb, nullptr,
      kBT, kC, kC, kC, kC, kC, 0, (long)kC * kC, (long)kBT * kC, 1.0f);
  gemm_bt<2, false, false><<<dim3(4, 64, 1), 256, 0, stream>>>(xb, wvt, vt, nullptr,
      kBT, kC, kC, kC, kC, kBT, 0, 0, 0, 1.0f);

  // S[b] = scale * q[b] @ k[b]^T  (f32, causal tile-skip), staged in d_out
  gemm_bt<0, true, false><<<dim3(16, 16, 4), 256, 0, stream>>>(qb, kb, Sbuf, nullptr,
      kT, kT, kC, kC, kC, kT, (long)kT * kC, (long)kT * kC, (long)kT * kT, kScale);

  softmax_causal<<<kBT, 256, 0, stream>>>(Sbuf, Pbuf);

  // attn[b] = P[b] @ v[b] with causal K-cap (P cols >= rowtile_end are zero)
  gemm_bt<1, false, true><<<dim3(4, 16, 4), 256, 0, stream>>>(Pbuf, vt, attn, nullptr,
      kT, kC, kT, kT, kBT, kC, (long)kT * kT, (long)kT, (long)kT * kC, 1.0f);

  // logits = attn @ Wo + bo : 256x128 BK=32 2-blocks/CU kernel, fused CE partials
  gemm_logits_ce<<<dim3((kBT / 256) * (kV / 128)), 512, 0, stream>>>(
      attn, wot, out, bo, cepart);

  ce_reduce<<<kBT / 4, 256, 0, stream>>>(out, cepart, targets, nll, kV / 128);
  loss_reduce<<<1, 256, 0, stream>>>(nll, out + (long)kBT * kV);
}